// Round 10
// baseline (200.974 us; speedup 1.0000x reference)
//
#include <hip/hip_runtime.h>
#include <math.h>

#define NN 768
#define DD 128
#define AA 312
#define HH 8
#define CEPS 1e-8f

typedef __attribute__((ext_vector_type(8))) short s8b;   // 8 x bf16
typedef __attribute__((ext_vector_type(4))) float f4v;   // MFMA C/D

__device__ __forceinline__ float wave_sum(float v) {
    #pragma unroll
    for (int o = 32; o; o >>= 1) v += __shfl_down(v, o, 64);
    return v;
}
__device__ __forceinline__ float wave_max(float v) {
    #pragma unroll
    for (int o = 32; o; o >>= 1) v = fmaxf(v, __shfl_down(v, o, 64));
    return v;
}
__device__ __forceinline__ unsigned short f2bf(float f) {
    unsigned u = __float_as_uint(f);
    u += 0x7FFFu + ((u >> 16) & 1u);
    return (unsigned short)(u >> 16);
}

struct KParams {
    const float *visual, *semantic, *attribute;
    const float *Wvn, *bvn, *gvn, *betavn, *Wve1, *bve1, *Wve2, *bve2;
    const float *Wsn, *bsn, *gsn, *betasn, *Wse1, *bse1, *Wse2, *bse2;
    float *vp, *sp, *ve2, *se2;
    float *simv, *sima, *WvnT, *WsnT, *cvec1, *cvec2;
    float *nrmv, *nrma, *ve, *se;
    short *vpb, *spb;
};

// ---------------- K1: MFMA bf16x2-split gram (raw G) + diag norms + W transposes -----------
__global__ __launch_bounds__(256) void gram_mfma_kernel(KParams p) {
    __shared__ __align__(16) unsigned short AH[64 * 40];
    __shared__ __align__(16) unsigned short AL[64 * 40];
    __shared__ __align__(16) unsigned short BH[64 * 40];
    __shared__ __align__(16) unsigned short BL[64 * 40];
    const int task = blockIdx.x;
    const int tid = threadIdx.x;
    if (task < 288) {
        const bool isv = (task < 144);
        const int tt = isv ? task : task - 144;
        const int bi = tt / 12, bj = tt % 12;
        const float* M = isv ? p.visual : p.attribute;
        float* G = isv ? p.simv : p.sima;
        float* nrm = isv ? p.nrmv : p.nrma;
        const int K = isv ? DD : AA;
        const int i0 = bi * 64, j0 = bj * 64;
        const int w = tid >> 6, lane = tid & 63;
        const int m = lane & 15, q = lane >> 4;
        f4v acc[4] = {{0.f, 0.f, 0.f, 0.f}, {0.f, 0.f, 0.f, 0.f},
                      {0.f, 0.f, 0.f, 0.f}, {0.f, 0.f, 0.f, 0.f}};
        const int nchunk = (K + 31) >> 5;
        const int srow = tid >> 2, sq = (tid & 3) * 8;
        for (int c = 0; c < nchunk; ++c) {
            const int kc = c * 32;
            __syncthreads();
            #pragma unroll
            for (int h = 0; h < 2; ++h) {
                const int col = sq + h * 4;
                float4 a = {0.f, 0.f, 0.f, 0.f}, b = {0.f, 0.f, 0.f, 0.f};
                if (kc + col + 4 <= K) {
                    a = *(const float4*)(M + (size_t)(i0 + srow) * K + kc + col);
                    b = *(const float4*)(M + (size_t)(j0 + srow) * K + kc + col);
                }
                const float av[4] = {a.x, a.y, a.z, a.w};
                const float bv[4] = {b.x, b.y, b.z, b.w};
                #pragma unroll
                for (int e = 0; e < 4; ++e) {
                    const unsigned short ah = f2bf(av[e]);
                    const float ahf = __uint_as_float((unsigned)ah << 16);
                    const unsigned short al = f2bf(av[e] - ahf);
                    const unsigned short bh = f2bf(bv[e]);
                    const float bhf = __uint_as_float((unsigned)bh << 16);
                    const unsigned short bl = f2bf(bv[e] - bhf);
                    AH[srow * 40 + col + e] = ah;
                    AL[srow * 40 + col + e] = al;
                    BH[srow * 40 + col + e] = bh;
                    BL[srow * 40 + col + e] = bl;
                }
            }
            __syncthreads();
            const s8b ah8 = *(const s8b*)&AH[(w * 16 + m) * 40 + q * 8];
            const s8b al8 = *(const s8b*)&AL[(w * 16 + m) * 40 + q * 8];
            #pragma unroll
            for (int jt = 0; jt < 4; ++jt) {
                const s8b bh8 = *(const s8b*)&BH[(jt * 16 + m) * 40 + q * 8];
                const s8b bl8 = *(const s8b*)&BL[(jt * 16 + m) * 40 + q * 8];
                acc[jt] = __builtin_amdgcn_mfma_f32_16x16x32_bf16(ah8, bh8, acc[jt], 0, 0, 0);
                acc[jt] = __builtin_amdgcn_mfma_f32_16x16x32_bf16(ah8, bl8, acc[jt], 0, 0, 0);
                acc[jt] = __builtin_amdgcn_mfma_f32_16x16x32_bf16(al8, bh8, acc[jt], 0, 0, 0);
            }
        }
        #pragma unroll
        for (int jt = 0; jt < 4; ++jt) {
            #pragma unroll
            for (int r = 0; r < 4; ++r) {
                G[(size_t)(i0 + w * 16 + q * 4 + r) * NN + j0 + jt * 16 + m] = acc[jt][r];
                if (bi == bj && jt == w && m == q * 4 + r)
                    nrm[i0 + w * 16 + m] = sqrtf(fmaxf(acc[jt][r], 0.f));
            }
        }
    } else {
        float* smem = (float*)AH;
        const int u = task - 288;
        const float* S = (u >= 16) ? p.Wsn : p.Wvn;
        float* Dt = (u >= 16) ? p.WsnT : p.WvnT;
        const int tile = u & 15;
        const int c0 = (tile & 3) * 32, r0 = (tile >> 2) * 32;
        const int tx = tid & 31, ty = tid >> 5;
        #pragma unroll
        for (int rr = ty; rr < 32; rr += 8)
            smem[rr * 33 + tx] = S[(size_t)(r0 + rr) * DD + c0 + tx];
        __syncthreads();
        #pragma unroll
        for (int rr = ty; rr < 32; rr += 8)
            Dt[(size_t)(c0 + rr) * DD + r0 + tx] = smem[tx * 33 + rr];
    }
}

// Two concurrent 768-float softmaxes: waves 0-3 on A, waves 4-7 on B. 3 barriers.
__device__ void softmax768_pair(float* A, float* B, int tid, float* red) {
    float* buf = (tid < 256) ? A : B;
    const int st = tid & 255;
    const int g = tid >> 8;
    const int w4 = (tid >> 6) & 3;
    float v0 = buf[st], v1 = buf[st + 256], v2 = buf[st + 512];
    float m = wave_max(fmaxf(fmaxf(v0, v1), v2));
    if ((tid & 63) == 0) red[g * 8 + w4] = m;
    __syncthreads();
    m = fmaxf(fmaxf(red[g * 8], red[g * 8 + 1]), fmaxf(red[g * 8 + 2], red[g * 8 + 3]));
    float e0 = __expf(v0 - m), e1 = __expf(v1 - m), e2 = __expf(v2 - m);
    float sw = wave_sum(e0 + e1 + e2);
    if ((tid & 63) == 0) red[g * 8 + 4 + w4] = sw;
    __syncthreads();
    const float s = red[g * 8 + 4] + red[g * 8 + 5] + red[g * 8 + 6] + red[g * 8 + 7];
    const float inv = 1.f / s;
    buf[st] = e0 * inv;
    buf[st + 256] = e1 * inv;
    buf[st + 512] = e2 * inv;
    __syncthreads();
}

// 512-thread softmax over one 768-float LDS row, in place. 3 barriers.
__device__ void block_softmax768(float* buf, int tid, float* red) {
    const int w = tid >> 6, lane = tid & 63;
    float v0 = buf[tid];
    float v1 = (tid < NN - 512) ? buf[tid + 512] : -3.4e38f;
    float m = wave_max(fmaxf(v0, v1));
    if (lane == 0) red[w] = m;
    __syncthreads();
    m = red[0];
    #pragma unroll
    for (int i = 1; i < 8; ++i) m = fmaxf(m, red[i]);
    float e0 = __expf(v0 - m);
    float e1 = (tid < NN - 512) ? __expf(v1 - m) : 0.f;
    float sw = wave_sum(e0 + e1);
    if (lane == 0) red[8 + w] = sw;
    __syncthreads();
    float s = 0.f;
    #pragma unroll
    for (int i = 0; i < 8; ++i) s += red[8 + i];
    const float inv = 1.f / s;
    buf[tid] = e0 * inv;
    if (tid < NN - 512) buf[tid + 512] = e1 * inv;
    __syncthreads();
}

// single-row node tail. ep/ex: softmaxed rows (LDS). preg comes from ep (the "edge" operand).
__device__ void node_core1(const float* __restrict__ P, float* ep, float* ex,
                           const float* __restrict__ WT, const float* __restrict__ b,
                           const float* __restrict__ g, const float* __restrict__ beta,
                           float* __restrict__ out, const float* __restrict__ W1e,
                           short* __restrict__ outb, float* __restrict__ cvec, int i, int tid,
                           float* ppart, float* xpart, float* qs, float (*tps)[DD],
                           float* red) {
    {   // aggregation: 8 k-groups (one per wave) x 64 d-pairs; float2 P loads.
        const int kg = tid >> 6, dp = tid & 63, d0 = dp * 2;
        const float2* P2 = (const float2*)P;
        float a0 = 0.f, a1 = 0.f, b0 = 0.f, b1 = 0.f;
        const int kb = kg * 96;
        #pragma unroll 8
        for (int it = 0; it < 96; ++it) {
            const int k = kb + it;
            const float2 pv = P2[(size_t)k * 64 + dp];
            const float e0 = ep[k], f0 = ex[k];
            a0 = fmaf(e0, pv.x, a0); a1 = fmaf(e0, pv.y, a1);
            b0 = fmaf(f0, pv.x, b0); b1 = fmaf(f0, pv.y, b1);
        }
        ppart[kg * 130 + d0] = a0; ppart[kg * 130 + d0 + 1] = a1;
        xpart[kg * 130 + d0] = b0; xpart[kg * 130 + d0 + 1] = b1;
    }
    __syncthreads();
    const int d = tid & 127;
    float preg = 0.f;
    if (tid < 128) {
        float pv = 0.f, xv = 0.f;
        #pragma unroll
        for (int kk = 0; kk < 8; ++kk) {
            pv += ppart[kk * 130 + d];
            xv += xpart[kk * 130 + d];
        }
        qs[d] = pv + xv;
        preg = pv;
    }
    __syncthreads();
    {   // transform: 4 col-chunks x 128 d
        const int sc = tid >> 7;
        float t = (sc == 0) ? b[d] : 0.f;
        const int c0 = sc * 32;
        #pragma unroll 4
        for (int c = c0; c < c0 + 32; ++c) t = fmaf(qs[c], WT[(size_t)c * DD + d], t);
        tps[sc][d] = t;
    }
    __syncthreads();
    float tval = 0.f;
    if (tid < 128) tval = tps[0][d] + tps[1][d] + tps[2][d] + tps[3][d];
    float sm = wave_sum(tid < 128 ? tval : 0.f);
    if ((tid & 63) == 0 && tid < 128) red[tid >> 6] = sm;
    __syncthreads();
    if (tid < 128) tval -= (red[0] + red[1]) * (1.f / DD);
    float s2 = wave_sum(tid < 128 ? tval * tval : 0.f);
    if ((tid & 63) == 0 && tid < 128) red[8 + (tid >> 6)] = s2;
    __syncthreads();
    if (tid < 128) {
        const float var = (red[8] + red[9]) * (1.f / DD);
        const float ln = tval * rsqrtf(var + 1e-5f) * g[d] + beta[d];
        const float val = fmaxf(ln, 0.f) + preg;
        out[(size_t)i * DD + d] = val;
        outb[(size_t)i * DD + d] = (short)f2bf(val);
        qs[d] = val;
    }
    __syncthreads();
    if (tid < 128) {
        const int r = tid >> 4, l16 = tid & 15;
        float ssum = 0.f;
        #pragma unroll
        for (int t = 0; t < 8; ++t) {
            const int k = l16 + 16 * t;
            const float pv = qs[k];
            ssum = fmaf(W1e[r * DD + k], pv * pv, ssum);
        }
        #pragma unroll
        for (int o = 8; o; o >>= 1) ssum += __shfl_down(ssum, o, 16);
        if (l16 == 0) cvec[(size_t)i * HH + r] = ssum;
    }
}

// ---------------- K2: node1 (1 row/block, 768 blocks, 512 thr) ----------------
__global__ __launch_bounds__(512) void node1_kernel(KParams p) {
    __shared__ __align__(16) float ep[NN], ex[NN];
    __shared__ __align__(16) float ppart[8 * 130], xpart[8 * 130];
    __shared__ __align__(16) float qs[DD], tps[4][DD];
    __shared__ float red[16];
    const int i = blockIdx.x;
    const int tid = threadIdx.x;
    if (tid < 192) ((float4*)ep)[tid] = ((const float4*)(p.simv + (size_t)i * NN))[tid];
    else if (tid < 384) ((float4*)ex)[tid - 192] = ((const float4*)(p.sima + (size_t)i * NN))[tid - 192];
    __syncthreads();
    {   // normalize both rows: val = G*10/max(ni*nj, eps)
        const float niv = p.nrmv[i], nia = p.nrma[i];
        const int k0 = tid, k1 = tid + 512;
        ep[k0] = ep[k0] * 10.f / fmaxf(niv * p.nrmv[k0], CEPS);
        ex[k0] = ex[k0] * 10.f / fmaxf(nia * p.nrma[k0], CEPS);
        if (k1 < NN) {
            ep[k1] = ep[k1] * 10.f / fmaxf(niv * p.nrmv[k1], CEPS);
            ex[k1] = ex[k1] * 10.f / fmaxf(nia * p.nrma[k1], CEPS);
        }
    }
    __syncthreads();
    softmax768_pair(ep, ex, tid, red);
    if (tid < 192) ((float4*)(p.ve + (size_t)i * NN))[tid] = ((float4*)ep)[tid];
    else if (tid < 384) ((float4*)(p.se + (size_t)i * NN))[tid - 192] = ((float4*)ex)[tid - 192];
    node_core1(p.visual, ep, ex, p.WvnT, p.bvn, p.gvn, p.betavn, p.vp, p.Wve1, p.vpb, p.cvec1,
               i, tid, ppart, xpart, qs, tps, red);
}

// single-row edge logits into Ls (LDS, unsoftmaxed). Lv = pre-softmaxed last_edge row.
__device__ void edge_core1(const short* __restrict__ PRb, const float* __restrict__ cvec,
                           const float* __restrict__ b1, const float* __restrict__ W2,
                           const float* __restrict__ b2, float invtemp, int i, int tid,
                           float* pi, float* w1s, short* a_sw, float* Lv, float* Ls) {
    const int lane = tid & 63, wave = tid >> 6;
    if (tid < 256) {  // A fragments: m = hidden r for m<8, zero rows 8-15. k = t*32+q2*8+e
        const int t = tid >> 6, m = lane & 15, q2 = lane >> 4;
        const int r = m & 7;
        const int kb = t * 32 + q2 * 8;
        s8b av;
        #pragma unroll
        for (int e = 0; e < 8; ++e)
            av[e] = (m < 8) ? (short)f2bf(pi[kb + e] * w1s[r * DD + kb + e]) : (short)0;
        *(s8b*)&a_sw[(t * 64 + lane) * 8] = av;
    }
    __syncthreads();
    s8b af[4];
    #pragma unroll
    for (int t = 0; t < 4; ++t) af[t] = *(const s8b*)&a_sw[(t * 64 + lane) * 8];
    const int q = lane >> 4, n = lane & 15;
    const int rbase = (q & 1) * 4;
    const float4 ci4 = *(const float4*)&cvec[(size_t)i * HH + rbase];
    const float4 b14 = *(const float4*)&b1[rbase];
    const float4 w24 = *(const float4*)&W2[rbase];
    const float b2s = b2[0];
    #pragma unroll
    for (int s = 0; s < 6; ++s) {
        const int j = wave * 96 + s * 16 + n;
        f4v acc = {0.f, 0.f, 0.f, 0.f};
        #pragma unroll
        for (int t = 0; t < 4; ++t) {
            const s8b bf = *(const s8b*)(PRb + (size_t)j * DD + t * 32 + q * 8);
            acc = __builtin_amdgcn_mfma_f32_16x16x32_bf16(af[t], bf, acc, 0, 0, 0);
        }
        const float4 cj = *(const float4*)&cvec[(size_t)j * HH + rbase];
        float z[4];
        z[0] = ci4.x + cj.x - 2.f * acc[0] + b14.x;
        z[1] = ci4.y + cj.y - 2.f * acc[1] + b14.y;
        z[2] = ci4.z + cj.z - 2.f * acc[2] + b14.z;
        z[3] = ci4.w + cj.w - 2.f * acc[3] + b14.w;
        float s1 = z[0] + z[1] + z[2] + z[3];
        float s2 = z[0] * z[0] + z[1] * z[1] + z[2] * z[2] + z[3] * z[3];
        s1 += __shfl_xor(s1, 16, 64);
        s2 += __shfl_xor(s2, 16, 64);
        const float mean = s1 * (1.f / HH);
        const float var = fmaxf(s2 * (1.f / HH) - mean * mean, 0.f);
        const float istd = rsqrtf(var + 1e-5f);
        float a2 = 0.f;
        a2 = fmaf(fmaxf((z[0] - mean) * istd, 0.f), w24.x, a2);
        a2 = fmaf(fmaxf((z[1] - mean) * istd, 0.f), w24.y, a2);
        a2 = fmaf(fmaxf((z[2] - mean) * istd, 0.f), w24.z, a2);
        a2 = fmaf(fmaxf((z[3] - mean) * istd, 0.f), w24.w, a2);
        a2 += __shfl_xor(a2, 16, 64);
        const float tv = tanhf(a2 + b2s);
        const float lv = Lv[j];
        if (q == 0) Ls[j] = tv * (lv + CEPS) * invtemp;
    }
    __syncthreads();
}

// ---------------- K3: edge1 + node2 fused (1 row/block, 768 blocks, 512 thr) ----------------
__global__ __launch_bounds__(512) void edge_node_kernel(KParams p) {
    __shared__ __align__(16) float pi[DD];
    __shared__ __align__(16) float w1s[HH * DD];
    __shared__ __align__(16) short a_sw[4 * 64 * 8];
    __shared__ __align__(16) float Lv[NN], Ls[NN], ep[NN];
    __shared__ __align__(16) float ppart[8 * 130], xpart[8 * 130];
    __shared__ __align__(16) float qs[DD], tps[4][DD];
    __shared__ float red[16];
    const int i = blockIdx.x;
    const int tid = threadIdx.x;
    if (tid < 32) ((float4*)pi)[tid] = ((const float4*)(p.vp + (size_t)i * DD))[tid];
    if (tid < 256) ((float4*)w1s)[tid] = ((const float4*)p.Wve1)[tid];
    if (tid < 192) ((float4*)Lv)[tid] = ((const float4*)(p.ve + (size_t)i * NN))[tid];
    else if (tid < 384) ((float4*)ep)[tid - 192] = ((const float4*)(p.se + (size_t)i * NN))[tid - 192];
    __syncthreads();
    edge_core1(p.vpb, p.cvec1, p.bve1, p.Wve2, p.bve2, 0.1f, i, tid, pi, w1s, a_sw, Lv, Ls);
    block_softmax768(Ls, tid, red);
    if (tid < 192) ((float4*)(p.ve2 + (size_t)i * NN))[tid] = ((float4*)Ls)[tid];
    // node2 row i: ep = se row (edge, gives preg), ex = Ls (= ve2 row, last_edge/extra)
    node_core1(p.semantic, ep, Ls, p.WsnT, p.bsn, p.gsn, p.betasn, p.sp, p.Wse1, p.spb,
               p.cvec2, i, tid, ppart, xpart, qs, tps, red);
}

// ---------------- K4: edge2 (1 row/block, 768 blocks, 512 thr) ----------------
__global__ __launch_bounds__(512) void edge2_kernel(KParams p) {
    __shared__ __align__(16) float pi[DD];
    __shared__ __align__(16) float w1s[HH * DD];
    __shared__ __align__(16) short a_sw[4 * 64 * 8];
    __shared__ __align__(16) float Lv[NN], Ls[NN];
    __shared__ float red[16];
    const int i = blockIdx.x;
    const int tid = threadIdx.x;
    if (tid < 32) ((float4*)pi)[tid] = ((const float4*)(p.sp + (size_t)i * DD))[tid];
    if (tid < 256) ((float4*)w1s)[tid] = ((const float4*)p.Wse1)[tid];
    if (tid < 192) ((float4*)Lv)[tid] = ((const float4*)(p.se + (size_t)i * NN))[tid];
    __syncthreads();
    edge_core1(p.spb, p.cvec2, p.bse1, p.Wse2, p.bse2, 0.1f, i, tid, pi, w1s, a_sw, Lv, Ls);
    block_softmax768(Ls, tid, red);
    float* d0 = p.se2 + (size_t)i * NN;
    d0[tid] = Ls[tid];
    if (tid < NN - 512) d0[tid + 512] = Ls[tid + 512];
}

extern "C" void kernel_launch(void* const* d_in, const int* in_sizes, int n_in, void* d_out,
                              int out_size, void* d_ws, size_t ws_size, hipStream_t stream) {
    KParams kp;
    kp.visual    = (const float*)d_in[0];
    kp.semantic  = (const float*)d_in[1];
    kp.attribute = (const float*)d_in[2];
    kp.Wvn  = (const float*)d_in[3];
    kp.bvn  = (const float*)d_in[4];
    kp.gvn  = (const float*)d_in[5];
    kp.betavn = (const float*)d_in[6];
    kp.Wve1 = (const float*)d_in[7];
    kp.bve1 = (const float*)d_in[8];
    kp.Wve2 = (const float*)d_in[9];
    kp.bve2 = (const float*)d_in[10];
    kp.Wsn  = (const float*)d_in[11];
    kp.bsn  = (const float*)d_in[12];
    kp.gsn  = (const float*)d_in[13];
    kp.betasn = (const float*)d_in[14];
    kp.Wse1 = (const float*)d_in[15];
    kp.bse1 = (const float*)d_in[16];
    kp.Wse2 = (const float*)d_in[17];
    kp.bse2 = (const float*)d_in[18];

    float* out = (float*)d_out;
    kp.vp  = out;              // 768*128
    kp.sp  = out + 98304;      // 768*128
    kp.ve2 = out + 196608;     // 768*768
    kp.se2 = out + 786432;     // 768*768

    float* ws = (float*)d_ws;
    kp.simv  = ws;             // 768*768 RAW gram
    kp.sima  = ws + 589824;
    kp.ve    = ws + 1179648;   // materialized softmax(norm(simv))
    kp.se    = ws + 1769472;   // materialized softmax(norm(sima))
    kp.WvnT  = ws + 2949120;   // 128*128
    kp.WsnT  = ws + 2965504;
    kp.cvec1 = ws + 2981888;   // 768*8
    kp.cvec2 = ws + 2988032;
    kp.vpb   = (short*)(ws + 2994176);  // 768*128 bf16 (49152 floats)
    kp.spb   = (short*)(ws + 3043328);
    kp.nrmv  = ws + 3092480;   // 768
    kp.nrma  = ws + 3093248;   // 768

    gram_mfma_kernel<<<320, 256, 0, stream>>>(kp);
    node1_kernel<<<NN, 512, 0, stream>>>(kp);
    edge_node_kernel<<<NN, 512, 0, stream>>>(kp);
    edge2_kernel<<<NN, 512, 0, stream>>>(kp);
}

// Round 11
// 170.136 us; speedup vs baseline: 1.1813x; 1.1813x over previous
//
#include <hip/hip_runtime.h>
#include <math.h>

#define NN 768
#define DD 128
#define AA 312
#define HH 8
#define CEPS 1e-8f

typedef __attribute__((ext_vector_type(8))) short s8b;   // 8 x bf16
typedef __attribute__((ext_vector_type(4))) float f4v;   // MFMA C/D

__device__ __forceinline__ float wave_sum(float v) {
    #pragma unroll
    for (int o = 32; o; o >>= 1) v += __shfl_down(v, o, 64);
    return v;
}
__device__ __forceinline__ float wave_max(float v) {
    #pragma unroll
    for (int o = 32; o; o >>= 1) v = fmaxf(v, __shfl_down(v, o, 64));
    return v;
}
__device__ __forceinline__ unsigned short f2bf(float f) {
    unsigned u = __float_as_uint(f);
    u += 0x7FFFu + ((u >> 16) & 1u);
    return (unsigned short)(u >> 16);
}

struct KParams {
    const float *visual, *semantic, *attribute;
    const float *Wvn, *bvn, *gvn, *betavn, *Wve1, *bve1, *Wve2, *bve2;
    const float *Wsn, *bsn, *gsn, *betasn, *Wse1, *bse1, *Wse2, *bse2;
    float *vp, *sp, *ve2, *se2;
    float *simv, *sima, *WvnT, *WsnT, *cvec1, *cvec2;
    float *nrmv, *nrma, *ve, *se;
    short *vpb, *spb, *visb, *semb;
};

// ---------------- K1: MFMA bf16x2-split gram + diag norms + W transposes + bf16 copies -----
__global__ __launch_bounds__(256) void gram_mfma_kernel(KParams p) {
    __shared__ __align__(16) unsigned short AH[64 * 40];
    __shared__ __align__(16) unsigned short AL[64 * 40];
    __shared__ __align__(16) unsigned short BH[64 * 40];
    __shared__ __align__(16) unsigned short BL[64 * 40];
    const int task = blockIdx.x;
    const int tid = threadIdx.x;
    if (task < 288) {
        const bool isv = (task < 144);
        const int tt = isv ? task : task - 144;
        const int bi = tt / 12, bj = tt % 12;
        const float* M = isv ? p.visual : p.attribute;
        float* G = isv ? p.simv : p.sima;
        float* nrm = isv ? p.nrmv : p.nrma;
        const int K = isv ? DD : AA;
        const int i0 = bi * 64, j0 = bj * 64;
        const int w = tid >> 6, lane = tid & 63;
        const int m = lane & 15, q = lane >> 4;
        f4v acc[4] = {{0.f, 0.f, 0.f, 0.f}, {0.f, 0.f, 0.f, 0.f},
                      {0.f, 0.f, 0.f, 0.f}, {0.f, 0.f, 0.f, 0.f}};
        const int nchunk = (K + 31) >> 5;
        const int srow = tid >> 2, sq = (tid & 3) * 8;
        for (int c = 0; c < nchunk; ++c) {
            const int kc = c * 32;
            __syncthreads();
            #pragma unroll
            for (int h = 0; h < 2; ++h) {
                const int col = sq + h * 4;
                float4 a = {0.f, 0.f, 0.f, 0.f}, b = {0.f, 0.f, 0.f, 0.f};
                if (kc + col + 4 <= K) {
                    a = *(const float4*)(M + (size_t)(i0 + srow) * K + kc + col);
                    b = *(const float4*)(M + (size_t)(j0 + srow) * K + kc + col);
                }
                const float av[4] = {a.x, a.y, a.z, a.w};
                const float bv[4] = {b.x, b.y, b.z, b.w};
                #pragma unroll
                for (int e = 0; e < 4; ++e) {
                    const unsigned short ah = f2bf(av[e]);
                    const float ahf = __uint_as_float((unsigned)ah << 16);
                    const unsigned short al = f2bf(av[e] - ahf);
                    const unsigned short bh = f2bf(bv[e]);
                    const float bhf = __uint_as_float((unsigned)bh << 16);
                    const unsigned short bl = f2bf(bv[e] - bhf);
                    AH[srow * 40 + col + e] = ah;
                    AL[srow * 40 + col + e] = al;
                    BH[srow * 40 + col + e] = bh;
                    BL[srow * 40 + col + e] = bl;
                }
            }
            __syncthreads();
            const s8b ah8 = *(const s8b*)&AH[(w * 16 + m) * 40 + q * 8];
            const s8b al8 = *(const s8b*)&AL[(w * 16 + m) * 40 + q * 8];
            #pragma unroll
            for (int jt = 0; jt < 4; ++jt) {
                const s8b bh8 = *(const s8b*)&BH[(jt * 16 + m) * 40 + q * 8];
                const s8b bl8 = *(const s8b*)&BL[(jt * 16 + m) * 40 + q * 8];
                acc[jt] = __builtin_amdgcn_mfma_f32_16x16x32_bf16(ah8, bh8, acc[jt], 0, 0, 0);
                acc[jt] = __builtin_amdgcn_mfma_f32_16x16x32_bf16(ah8, bl8, acc[jt], 0, 0, 0);
                acc[jt] = __builtin_amdgcn_mfma_f32_16x16x32_bf16(al8, bh8, acc[jt], 0, 0, 0);
            }
        }
        #pragma unroll
        for (int jt = 0; jt < 4; ++jt) {
            #pragma unroll
            for (int r = 0; r < 4; ++r) {
                G[(size_t)(i0 + w * 16 + q * 4 + r) * NN + j0 + jt * 16 + m] = acc[jt][r];
                if (bi == bj && jt == w && m == q * 4 + r)
                    nrm[i0 + w * 16 + m] = sqrtf(fmaxf(acc[jt][r], 0.f));
            }
        }
    } else if (task < 320) {
        float* smem = (float*)AH;
        const int u = task - 288;
        const float* S = (u >= 16) ? p.Wsn : p.Wvn;
        float* Dt = (u >= 16) ? p.WsnT : p.WvnT;
        const int tile = u & 15;
        const int c0 = (tile & 3) * 32, r0 = (tile >> 2) * 32;
        const int tx = tid & 31, ty = tid >> 5;
        #pragma unroll
        for (int rr = ty; rr < 32; rr += 8)
            smem[rr * 33 + tx] = S[(size_t)(r0 + rr) * DD + c0 + tx];
        __syncthreads();
        #pragma unroll
        for (int rr = ty; rr < 32; rr += 8)
            Dt[(size_t)(c0 + rr) * DD + r0 + tx] = smem[tx * 33 + rr];
    } else {
        // bf16 copies of visual (tasks 320-331) / semantic (tasks 332-343); 8192 elems/block
        const int u = task - 320;
        const bool isv = (u < 12);
        const float* src = isv ? p.visual : p.semantic;
        short* dst = isv ? p.visb : p.semb;
        const int base = (isv ? u : u - 12) * 8192;
        for (int e = tid * 4; e < 8192; e += 1024) {
            const float4 v = *(const float4*)(src + base + e);
            const unsigned lo = (unsigned)f2bf(v.x) | ((unsigned)f2bf(v.y) << 16);
            const unsigned hi = (unsigned)f2bf(v.z) | ((unsigned)f2bf(v.w) << 16);
            *(uint2*)(dst + base + e) = make_uint2(lo, hi);
        }
    }
}

// Two concurrent 768-float softmaxes: waves 0-3 on A, waves 4-7 on B. 3 barriers.
__device__ void softmax768_pair(float* A, float* B, int tid, float* red) {
    float* buf = (tid < 256) ? A : B;
    const int st = tid & 255;
    const int g = tid >> 8;
    const int w4 = (tid >> 6) & 3;
    float v0 = buf[st], v1 = buf[st + 256], v2 = buf[st + 512];
    float m = wave_max(fmaxf(fmaxf(v0, v1), v2));
    if ((tid & 63) == 0) red[g * 8 + w4] = m;
    __syncthreads();
    m = fmaxf(fmaxf(red[g * 8], red[g * 8 + 1]), fmaxf(red[g * 8 + 2], red[g * 8 + 3]));
    float e0 = __expf(v0 - m), e1 = __expf(v1 - m), e2 = __expf(v2 - m);
    float sw = wave_sum(e0 + e1 + e2);
    if ((tid & 63) == 0) red[g * 8 + 4 + w4] = sw;
    __syncthreads();
    const float s = red[g * 8 + 4] + red[g * 8 + 5] + red[g * 8 + 6] + red[g * 8 + 7];
    const float inv = 1.f / s;
    buf[st] = e0 * inv;
    buf[st + 256] = e1 * inv;
    buf[st + 512] = e2 * inv;
    __syncthreads();
}

// normalize 2 raw gram rows in LDS: val = G*10/max(ni*nj, eps). Thread t owns {t, t+512}.
__device__ void norm_rows(float (*buf)[NN], const float* __restrict__ nrm, int i0, int tid) {
    const float n0 = nrm[i0], n1 = nrm[i0 + 1];
    for (int k = tid; k < NN; k += 512) {
        const float nj = nrm[k];
        buf[0][k] = buf[0][k] * 10.f / fmaxf(n0 * nj, CEPS);
        buf[1][k] = buf[1][k] * 10.f / fmaxf(n1 * nj, CEPS);
    }
}

// node tail. ep/ex: softmaxed rows in LDS. Pb: bf16 P matrix [768][128].
__device__ void node_core(const short* __restrict__ Pb, float (*ep)[NN], float (*ex)[NN],
                          const float* __restrict__ WT, const float* __restrict__ b,
                          const float* __restrict__ g, const float* __restrict__ beta,
                          float* __restrict__ out, const float* __restrict__ W1e,
                          short* __restrict__ outb, float* __restrict__ cvec, int i0, int tid,
                          float* ppart, float* xpart, float (*qs)[DD], float (*tps)[2][DD],
                          float* red) {
    // aggregation: 8 k-groups (one per wave) x 64 d-pairs; bf16-pair P loads.
    {
        const int kg = tid >> 6, dp = tid & 63, d0 = dp * 2;
        const unsigned* Pb2 = (const unsigned*)Pb;
        float a00 = 0.f, a01 = 0.f, a10 = 0.f, a11 = 0.f;
        float b00 = 0.f, b01 = 0.f, b10 = 0.f, b11 = 0.f;
        const int kb = kg * 96;
        #pragma unroll 8
        for (int i = 0; i < 96; ++i) {
            const int k = kb + i;
            const unsigned pvu = Pb2[(size_t)k * 64 + dp];
            const float pvx = __uint_as_float(pvu << 16);
            const float pvy = __uint_as_float(pvu & 0xffff0000u);
            const float e0 = ep[0][k], e1 = ep[1][k];
            const float f0 = ex[0][k], f1 = ex[1][k];
            a00 = fmaf(e0, pvx, a00); a01 = fmaf(e0, pvy, a01);
            a10 = fmaf(e1, pvx, a10); a11 = fmaf(e1, pvy, a11);
            b00 = fmaf(f0, pvx, b00); b01 = fmaf(f0, pvy, b01);
            b10 = fmaf(f1, pvx, b10); b11 = fmaf(f1, pvy, b11);
        }
        float* pp = ppart + kg * 260;  // [2][130] slab, stride 260 == 4 (mod 32) banks
        float* xp = xpart + kg * 260;
        pp[d0] = a00; pp[d0 + 1] = a01; pp[130 + d0] = a10; pp[130 + d0 + 1] = a11;
        xp[d0] = b00; xp[d0 + 1] = b01; xp[130 + d0] = b10; xp[130 + d0 + 1] = b11;
    }
    __syncthreads();
    const int rr = (tid >> 7) & 1, d = tid & 127;
    float preg = 0.f;
    if (tid < 256) {
        float p = 0.f, x = 0.f;
        #pragma unroll
        for (int kk = 0; kk < 8; ++kk) {
            p += ppart[kk * 260 + rr * 130 + d];
            x += xpart[kk * 260 + rr * 130 + d];
        }
        qs[rr][d] = p + x;
        preg = p;
    }
    __syncthreads();
    {
        const int sc = tid >> 8, rr2 = (tid >> 7) & 1;
        float t = (sc == 0) ? b[d] : 0.f;
        const int c0 = sc * 64;
        #pragma unroll 4
        for (int c = c0; c < c0 + 64; ++c) t = fmaf(qs[rr2][c], WT[(size_t)c * DD + d], t);
        tps[sc][rr2][d] = t;
    }
    __syncthreads();
    float tval = 0.f;
    if (tid < 256) tval = tps[0][rr][d] + tps[1][rr][d];
    float sm = wave_sum(tid < 256 ? tval : 0.f);
    if ((tid & 63) == 0) red[tid >> 6] = sm;
    __syncthreads();
    if (tid < 256) tval -= (red[2 * rr] + red[2 * rr + 1]) * (1.f / DD);
    float s2 = wave_sum(tid < 256 ? tval * tval : 0.f);
    if ((tid & 63) == 0) red[8 + (tid >> 6)] = s2;
    __syncthreads();
    if (tid < 256) {
        const float var = (red[8 + 2 * rr] + red[8 + 2 * rr + 1]) * (1.f / DD);
        const float ln = tval * rsqrtf(var + 1e-5f) * g[d] + beta[d];
        const float val = fmaxf(ln, 0.f) + preg;
        out[(size_t)(i0 + rr) * DD + d] = val;
        outb[(size_t)(i0 + rr) * DD + d] = (short)f2bf(val);
        qs[rr][d] = val;
    }
    __syncthreads();
    if (tid < 256) {
        const int row = tid >> 7, r = (tid >> 4) & 7, l16 = tid & 15;
        float ssum = 0.f;
        #pragma unroll
        for (int t = 0; t < 8; ++t) {
            const int k = l16 + 16 * t;
            const float pv = qs[row][k];
            ssum = fmaf(W1e[r * DD + k], pv * pv, ssum);
        }
        #pragma unroll
        for (int o = 8; o; o >>= 1) ssum += __shfl_down(ssum, o, 16);
        if (l16 == 0) cvec[(size_t)(i0 + row) * HH + r] = ssum;
    }
}

// ---------------- K2: node1 (2 rows/block, 512 thr) ----------------
__global__ __launch_bounds__(512) void node1_kernel(KParams p) {
    __shared__ __align__(16) float ep[2][NN], ex[2][NN];
    __shared__ __align__(16) float ppart[8 * 260], xpart[8 * 260];
    __shared__ __align__(16) float qs[2][DD], tps[2][2][DD];
    __shared__ float red[16];
    const int i0 = blockIdx.x * 2;
    const int tid = threadIdx.x;
    if (tid < 384) {
        ((float4*)ep)[tid] = ((const float4*)(p.simv + (size_t)i0 * NN))[tid];
        ((float4*)ex)[tid] = ((const float4*)(p.sima + (size_t)i0 * NN))[tid];
    }
    __syncthreads();
    norm_rows(ep, p.nrmv, i0, tid);
    norm_rows(ex, p.nrma, i0, tid);
    __syncthreads();
    softmax768_pair(ep[0], ex[0], tid, red);
    softmax768_pair(ep[1], ex[1], tid, red);
    if (tid < 384) {  // materialize ve/se rows for downstream kernels
        ((float4*)(p.ve + (size_t)i0 * NN))[tid] = ((float4*)ep)[tid];
        ((float4*)(p.se + (size_t)i0 * NN))[tid] = ((float4*)ex)[tid];
    }
    node_core(p.visb, ep, ex, p.WvnT, p.bvn, p.gvn, p.betavn, p.vp, p.Wve1, p.vpb, p.cvec1,
              i0, tid, ppart, xpart, qs, tps, red);
}

// edge logits into Ls (LDS, unsoftmaxed). Lv = pre-softmaxed last_edge rows.
__device__ void edge_core(const short* __restrict__ PRb, const float* __restrict__ cvec,
                          const float* __restrict__ W1, const float* __restrict__ b1,
                          const float* __restrict__ W2, const float* __restrict__ b2,
                          float invtemp, int i0, int tid, float (*pi)[DD], float* w1s,
                          short* a_sw, float (*Lv)[NN], float (*Ls)[NN]) {
    const int lane = tid & 63, wave = tid >> 6;
    if (tid < 256) {  // A fragments: m = il*8+r, k = t*32 + q2*8 + e
        const int t = tid >> 6, m = lane & 15, q2 = lane >> 4;
        const int il = m >> 3, r = m & 7;
        const int kb = t * 32 + q2 * 8;
        s8b av;
        #pragma unroll
        for (int e = 0; e < 8; ++e)
            av[e] = (short)f2bf(pi[il][kb + e] * w1s[r * DD + kb + e]);
        *(s8b*)&a_sw[(t * 64 + lane) * 8] = av;
    }
    __syncthreads();
    s8b af[4];
    #pragma unroll
    for (int t = 0; t < 4; ++t) af[t] = *(const s8b*)&a_sw[(t * 64 + lane) * 8];
    const int q = lane >> 4, n = lane & 15;
    const int rbase = (q & 1) * 4;
    const int il = q >> 1;
    const float4 ci4 = *(const float4*)&cvec[(size_t)(i0 + il) * HH + rbase];
    const float4 b14 = *(const float4*)&b1[rbase];
    const float4 w24 = *(const float4*)&W2[rbase];
    const float b2s = b2[0];
    #pragma unroll
    for (int s = 0; s < 6; ++s) {
        const int j = wave * 96 + s * 16 + n;
        f4v acc = {0.f, 0.f, 0.f, 0.f};
        #pragma unroll
        for (int t = 0; t < 4; ++t) {
            const s8b bf = *(const s8b*)(PRb + (size_t)j * DD + t * 32 + q * 8);
            acc = __builtin_amdgcn_mfma_f32_16x16x32_bf16(af[t], bf, acc, 0, 0, 0);
        }
        const float4 cj = *(const float4*)&cvec[(size_t)j * HH + rbase];
        float z[4];
        z[0] = ci4.x + cj.x - 2.f * acc[0] + b14.x;
        z[1] = ci4.y + cj.y - 2.f * acc[1] + b14.y;
        z[2] = ci4.z + cj.z - 2.f * acc[2] + b14.z;
        z[3] = ci4.w + cj.w - 2.f * acc[3] + b14.w;
        float s1 = z[0] + z[1] + z[2] + z[3];
        float s2 = z[0] * z[0] + z[1] * z[1] + z[2] * z[2] + z[3] * z[3];
        s1 += __shfl_xor(s1, 16, 64);
        s2 += __shfl_xor(s2, 16, 64);
        const float mean = s1 * (1.f / HH);
        const float var = fmaxf(s2 * (1.f / HH) - mean * mean, 0.f);
        const float istd = rsqrtf(var + 1e-5f);
        float a2 = 0.f;
        a2 = fmaf(fmaxf((z[0] - mean) * istd, 0.f), w24.x, a2);
        a2 = fmaf(fmaxf((z[1] - mean) * istd, 0.f), w24.y, a2);
        a2 = fmaf(fmaxf((z[2] - mean) * istd, 0.f), w24.z, a2);
        a2 = fmaf(fmaxf((z[3] - mean) * istd, 0.f), w24.w, a2);
        a2 += __shfl_xor(a2, 16, 64);
        const float tv = tanhf(a2 + b2s);
        const float lv = Lv[il][j];
        if ((q & 1) == 0) Ls[il][j] = tv * (lv + CEPS) * invtemp;
    }
    __syncthreads();
}

// ---------------- K3: edge1 + node2 fused (2 rows/block, 512 thr) ----------------
__global__ __launch_bounds__(512) void edge_node_kernel(KParams p) {
    __shared__ __align__(16) float pi[2][DD];
    __shared__ __align__(16) float w1s[HH * DD];
    __shared__ __align__(16) short a_sw[4 * 64 * 8];
    __shared__ __align__(16) float Lv[2][NN];
    __shared__ __align__(16) float Ls[2][NN];
    __shared__ __align__(16) float ep[2][NN];
    __shared__ __align__(16) float ppart[8 * 260], xpart[8 * 260];
    __shared__ __align__(16) float qs[2][DD], tps[2][2][DD];
    __shared__ float red[16];
    const int i0 = blockIdx.x * 2;
    const int tid = threadIdx.x;
    if (tid < 256) {
        pi[tid >> 7][tid & 127] = p.vp[(size_t)(i0 + (tid >> 7)) * DD + (tid & 127)];
        ((float4*)w1s)[tid] = ((const float4*)p.Wve1)[tid];
    }
    if (tid < 384) {
        ((float4*)Lv)[tid] = ((const float4*)(p.ve + (size_t)i0 * NN))[tid];
        ((float4*)ep)[tid] = ((const float4*)(p.se + (size_t)i0 * NN))[tid];
    }
    __syncthreads();
    edge_core(p.vpb, p.cvec1, p.Wve1, p.bve1, p.Wve2, p.bve2, 0.1f, i0, tid, pi, w1s, a_sw,
              Lv, Ls);
    softmax768_pair(Ls[0], Ls[1], tid, red);
    if (tid < 384)  // write ve2 rows
        ((float4*)(p.ve2 + (size_t)i0 * NN))[tid] = ((float4*)Ls)[tid];
    // node2: ep = se rows (pre-softmaxed), ex = Ls (= ve2 rows, in LDS)
    node_core(p.semb, ep, Ls, p.WsnT, p.bsn, p.gsn, p.betasn, p.sp, p.Wse1, p.spb,
              p.cvec2, i0, tid, ppart, xpart, qs, tps, red);
}

// ---------------- K4: edge2 (2 rows/block, 512 thr) ----------------
__global__ __launch_bounds__(512) void edge2_kernel(KParams p) {
    __shared__ __align__(16) float pi[2][DD];
    __shared__ __align__(16) float w1s[HH * DD];
    __shared__ __align__(16) short a_sw[4 * 64 * 8];
    __shared__ __align__(16) float Lv[2][NN];
    __shared__ __align__(16) float Ls[2][NN];
    __shared__ float red[16];
    const int i0 = blockIdx.x * 2;
    const int tid = threadIdx.x;
    if (tid < 256) {
        pi[tid >> 7][tid & 127] = p.sp[(size_t)(i0 + (tid >> 7)) * DD + (tid & 127)];
        ((float4*)w1s)[tid] = ((const float4*)p.Wse1)[tid];
    }
    if (tid < 384)
        ((float4*)Lv)[tid] = ((const float4*)(p.se + (size_t)i0 * NN))[tid];
    __syncthreads();
    edge_core(p.spb, p.cvec2, p.Wse1, p.bse1, p.Wse2, p.bse2, 0.1f, i0, tid, pi, w1s, a_sw,
              Lv, Ls);
    softmax768_pair(Ls[0], Ls[1], tid, red);
    float* d0 = p.se2 + (size_t)i0 * NN;
    float* d1 = p.se2 + (size_t)(i0 + 1) * NN;
    d0[tid] = Ls[0][tid];
    d1[tid] = Ls[1][tid];
    if (tid < NN - 512) {
        d0[tid + 512] = Ls[0][tid + 512];
        d1[tid + 512] = Ls[1][tid + 512];
    }
}

extern "C" void kernel_launch(void* const* d_in, const int* in_sizes, int n_in, void* d_out,
                              int out_size, void* d_ws, size_t ws_size, hipStream_t stream) {
    KParams kp;
    kp.visual    = (const float*)d_in[0];
    kp.semantic  = (const float*)d_in[1];
    kp.attribute = (const float*)d_in[2];
    kp.Wvn  = (const float*)d_in[3];
    kp.bvn  = (const float*)d_in[4];
    kp.gvn  = (const float*)d_in[5];
    kp.betavn = (const float*)d_in[6];
    kp.Wve1 = (const float*)d_in[7];
    kp.bve1 = (const float*)d_in[8];
    kp.Wve2 = (const float*)d_in[9];
    kp.bve2 = (const float*)d_in[10];
    kp.Wsn  = (const float*)d_in[11];
    kp.bsn  = (const float*)d_in[12];
    kp.gsn  = (const float*)d_in[13];
    kp.betasn = (const float*)d_in[14];
    kp.Wse1 = (const float*)d_in[15];
    kp.bse1 = (const float*)d_in[16];
    kp.Wse2 = (const float*)d_in[17];
    kp.bse2 = (const float*)d_in[18];

    float* out = (float*)d_out;
    kp.vp  = out;              // 768*128
    kp.sp  = out + 98304;      // 768*128
    kp.ve2 = out + 196608;     // 768*768
    kp.se2 = out + 786432;     // 768*768

    float* ws = (float*)d_ws;
    kp.simv  = ws;             // 768*768 RAW gram
    kp.sima  = ws + 589824;
    kp.ve    = ws + 1179648;   // materialized softmax(norm(simv))
    kp.se    = ws + 1769472;   // materialized softmax(norm(sima))
    kp.WvnT  = ws + 2949120;   // 128*128
    kp.WsnT  = ws + 2965504;
    kp.cvec1 = ws + 2981888;   // 768*8
    kp.cvec2 = ws + 2988032;
    kp.vpb   = (short*)(ws + 2994176);  // 768*128 bf16 (49152 floats)
    kp.spb   = (short*)(ws + 3043328);
    kp.nrmv  = ws + 3092480;   // 768
    kp.nrma  = ws + 3093248;   // 768
    kp.visb  = (short*)(ws + 3094016);  // 768*128 bf16 copy of visual
    kp.semb  = (short*)(ws + 3143168);  // 768*128 bf16 copy of semantic

    gram_mfma_kernel<<<344, 256, 0, stream>>>(kp);
    node1_kernel<<<NN / 2, 512, 0, stream>>>(kp);
    edge_node_kernel<<<NN / 2, 512, 0, stream>>>(kp);
    edge2_kernel<<<NN / 2, 512, 0, stream>>>(kp);
}